// Round 8
// baseline (394.689 us; speedup 1.0000x reference)
//
#include <hip/hip_runtime.h>
#include <hip/hip_bf16.h>

#define L2E 1.44269504088896f

typedef __attribute__((ext_vector_type(8))) short short8v;
typedef __attribute__((ext_vector_type(8))) _Float16 half8v;
typedef __attribute__((ext_vector_type(4))) float float4v;

__device__ __forceinline__ void gld16(void* lds, const void* gp) {
    __builtin_amdgcn_global_load_lds(
        (const __attribute__((address_space(1))) unsigned int*)gp,
        (__attribute__((address_space(3))) unsigned int*)lds, 16, 0, 0);
}
__device__ __forceinline__ unsigned pkbf(float a, float b) {
    unsigned r;
    asm("v_cvt_pk_bf16_f32 %0, %1, %2" : "=v"(r) : "v"(a), "v"(b));
    return r;
}
__device__ __forceinline__ unsigned pkrtz(float a, float b) {
    unsigned r;
    asm("v_cvt_pkrtz_f16_f32 %0, %1, %2" : "=v"(r) : "v"(a), "v"(b));
    return r;
}
__device__ __forceinline__ unsigned pkmul(unsigned a, unsigned b) {
    unsigned r;
    asm("v_pk_mul_f16 %0, %1, %2" : "=v"(r) : "v"(a), "v"(b));
    return r;
}
__device__ __forceinline__ unsigned pkmax(unsigned a, unsigned b) {
    unsigned r;
    asm("v_pk_max_f16 %0, %1, %2" : "=v"(r) : "v"(a), "v"(b));
    return r;
}

// ---------------- prep: pack adj, cvt x->bf16, all weight transposes ----------------
__device__ __forceinline__ void tp_body(const float* __restrict__ src,
                                        unsigned short* __restrict__ dst,
                                        int M, int F, int j0, int f0, float (*t)[17]) {
    int tid = threadIdx.x;
    int rr = tid >> 2, c0 = (tid & 3) * 4;
    float4 v = *(const float4*)&src[(size_t)(j0 + rr) * F + f0 + c0];
    t[rr][c0 + 0] = v.x;
    t[rr][c0 + 1] = v.y;
    t[rr][c0 + 2] = v.z;
    t[rr][c0 + 3] = v.w;
    __syncthreads();
    int f = tid >> 4, jl = (tid & 15) * 4;
    ushort4 o;
    o.x = (unsigned short)(pkbf(t[jl + 0][f], 0.f) & 0xffff);
    o.y = (unsigned short)(pkbf(t[jl + 1][f], 0.f) & 0xffff);
    o.z = (unsigned short)(pkbf(t[jl + 2][f], 0.f) & 0xffff);
    o.w = (unsigned short)(pkbf(t[jl + 3][f], 0.f) & 0xffff);
    *(ushort4*)&dst[(size_t)(f0 + f) * M + j0 + jl] = o;
}

__global__ __launch_bounds__(256) void prep_k(const int* __restrict__ adj,
                                              unsigned long long* __restrict__ mask,
                                              const float* __restrict__ x,
                                              unsigned short* __restrict__ xb,
                                              const float* __restrict__ W_att,
                                              const float* __restrict__ W_down,
                                              const float* __restrict__ W_out2,
                                              const float* __restrict__ W_out1,
                                              const float* __restrict__ W_deg3,
                                              unsigned short* __restrict__ WT,
                                              unsigned short* __restrict__ Wd3T) {
    __shared__ float tbuf[64][17];
    int bx = blockIdx.x, tid = threadIdx.x;
    if (bx < 65536) {                                   // pack adj bitmask
        size_t idx = (size_t)bx * 256 + tid;
        unsigned long long b = __ballot(adj[idx] > 0);
        if ((tid & 63) == 0) mask[idx >> 6] = b;
    } else if (bx < 66560) {                            // x -> bf16
        int i = (bx - 65536) * 256 + tid;
        float4 a = ((const float4*)x)[i * 2];
        float4 b = ((const float4*)x)[i * 2 + 1];
        uint4 o = {pkbf(a.x, a.y), pkbf(a.z, a.w), pkbf(b.x, b.y), pkbf(b.z, b.w)};
        ((uint4*)xb)[i] = o;
    } else if (bx < 66880) {                            // W_att/W_down/W_out2 -> WT[0..9]
        int r = bx - 66560;
        int z = r >> 5, rr = r & 31;
        const float* src = (z < 8) ? W_att + (size_t)z * 512 * 64 : ((z == 8) ? W_down : W_out2);
        tp_body(src, WT + (size_t)z * 64 * 512, 512, 64, (rr & 7) * 64, (rr >> 3) * 16, tbuf);
    } else if (bx < 66888) {                            // W_out1 -> WT rows 640..655
        int r = bx - 66880;
        tp_body(W_out1, WT + (size_t)640 * 512, 512, 16, r * 64, 0, tbuf);
    } else {                                            // W_deg3 [64][128] -> Wd3T [128][64]
        int r = bx - 66888;
        tp_body(W_deg3, Wd3T, 64, 128, 0, r * 16, tbuf);
    }
}

// ---------------- bf16 MFMA GEMM: C = A[MxK] @ Bt[NxK]^T ----------------
// OUTMODE 0: C f32 [Z][M][N] (+bias);  OUTMODE 1: C fp16 [Z][N][M] (transposed)
template <int BM, int BN, int OUTMODE>
__global__ __launch_bounds__(256) void gemmb_k(const __hip_bfloat16* __restrict__ A,
                                               const __hip_bfloat16* __restrict__ BtB,
                                               const float* __restrict__ bias,
                                               void* __restrict__ CB,
                                               int M, int N, int K) {
    constexpr int BK = 64;
    constexpr int MF = BM / 64;                      // row-frags per wave
    const int tid = threadIdx.x, lane = tid & 63, wv = tid >> 6;
    const int l16 = lane & 15, kq = lane >> 4;
    const int row0 = blockIdx.x * BM, col0 = blockIdx.y * BN;
    const size_t czs = (size_t)M * N;
    const __hip_bfloat16* Bt = BtB + (size_t)blockIdx.z * N * K;

    __shared__ __align__(16) __hip_bfloat16 As[2][BM][BK];

    auto stageA = [&](int k0, int b) {
#pragma unroll
        for (int c = 0; c < BM / 32; ++c) {
            int off = (tid + c * 256) * 16;
            int rr = off >> 7;
            int ch = (off >> 4) & 7;
            int chs = ch ^ (rr & 7);
            gld16((char*)&As[b][0][0] + off, A + (size_t)(row0 + rr) * K + k0 + chs * 8);
        }
    };

    float4v acc[MF][BN / 16];
#pragma unroll
    for (int mf = 0; mf < MF; ++mf)
#pragma unroll
        for (int nf = 0; nf < BN / 16; ++nf) acc[mf][nf] = (float4v){0.f, 0.f, 0.f, 0.f};

    const int rowb = wv * (BM / 4);
    const int nk = K / BK;
    stageA(0, 0);
    for (int t = 0; t < nk; ++t) {
        int k0 = t * BK, cur = t & 1;
        if (t + 1 < nk) stageA(k0 + BK, cur ^ 1);
        short8v bfr[BN / 16][2];
#pragma unroll
        for (int nf = 0; nf < BN / 16; ++nf)
#pragma unroll
            for (int ks = 0; ks < 2; ++ks)
                bfr[nf][ks] = *(const short8v*)(Bt + (size_t)(col0 + nf * 16 + l16) * K +
                                                k0 + ks * 32 + kq * 8);
        __syncthreads();
        const char* asb = (const char*)&As[cur][0][0];
#pragma unroll
        for (int ks = 0; ks < 2; ++ks) {
            short8v afr[MF];
#pragma unroll
            for (int mf = 0; mf < MF; ++mf) {
                int rr = rowb + mf * 16 + l16;
                afr[mf] = *(const short8v*)(asb + rr * 128 +
                                            ((ks * 64 + kq * 16) ^ ((rr & 7) << 4)));
            }
#pragma unroll
            for (int mf = 0; mf < MF; ++mf)
#pragma unroll
                for (int nf = 0; nf < BN / 16; ++nf)
                    acc[mf][nf] = __builtin_amdgcn_mfma_f32_16x16x32_bf16(
                        afr[mf], bfr[nf][ks], acc[mf][nf], 0, 0, 0);
        }
        __syncthreads();
    }

#pragma unroll
    for (int mf = 0; mf < MF; ++mf)
#pragma unroll
        for (int nf = 0; nf < BN / 16; ++nf) {
            int rb = row0 + rowb + mf * 16 + kq * 4;
            int col = col0 + nf * 16 + l16;
            if constexpr (OUTMODE == 0) {
                float bb = bias ? bias[col] : 0.f;
                float* C = (float*)CB + (size_t)blockIdx.z * czs;
#pragma unroll
                for (int e = 0; e < 4; ++e) C[(size_t)(rb + e) * N + col] = acc[mf][nf][e] + bb;
            } else {
                uint2 u = {pkrtz(acc[mf][nf][0], acc[mf][nf][1]),
                           pkrtz(acc[mf][nf][2], acc[mf][nf][3])};
                unsigned short* Ct = (unsigned short*)CB + (size_t)blockIdx.z * czs;
                *(uint2*)&Ct[(size_t)col * M + rb] = u;
            }
        }
}

// ---------------- f1/f2 from fp16 WhT (coalesced) ----------------
__global__ __launch_bounds__(256) void fvh_k(const _Float16* __restrict__ WhT,
                                             const float* __restrict__ a,
                                             float* __restrict__ f1, float* __restrict__ f2) {
    int zz = blockIdx.y;
    const _Float16* W = WhT + (size_t)zz * 64 * 4096;
    const float* az = a + (size_t)zz * 128;
    int i = blockIdx.x * 256 + threadIdx.x;
    float s1 = 0.f, s2 = 0.f;
    for (int k = 0; k < 64; k++) {
        float ww = (float)W[(size_t)k * 4096 + i];
        s1 = fmaf(ww, az[k], s1);
        s2 = fmaf(ww, az[64 + k], s2);
    }
    f1[(size_t)zz * 4096 + i] = s1;
    f2[(size_t)zz * 4096 + i] = s2;
}

__global__ __launch_bounds__(256) void fvo_k(const _Float16* __restrict__ Wh12T,
                                             const float* __restrict__ a2,
                                             const float* __restrict__ a1,
                                             float* __restrict__ f1o, float* __restrict__ f2o) {
    int y = blockIdx.y;
    const _Float16* W = Wh12T + (y ? (size_t)64 * 4096 : 0);
    const float* a = y ? a1 : a2;
    int D = y ? 16 : 64;
    int i = blockIdx.x * 256 + threadIdx.x;
    float s1 = 0.f, s2 = 0.f;
    for (int k = 0; k < D; k++) {
        float ww = (float)W[(size_t)k * 4096 + i];
        s1 = fmaf(ww, a[k], s1);
        s2 = fmaf(ww, a[D + k], s2);
    }
    f1o[(size_t)y * 4096 + i] = s1;
    f2o[(size_t)y * 4096 + i] = s2;
}

// ---------------- per-batch max of f2 + fp16 pn pair-table ----------------
__global__ __launch_bounds__(256) void rmaxpn_k(const float* __restrict__ f2B,
                                                float* __restrict__ M2out,
                                                uint2* __restrict__ pnB) {
    int z = blockIdx.x, tid = threadIdx.x;
    const float* f2 = f2B + (size_t)z * 4096;
    uint2* pn = pnB + (size_t)z * 2048;
    __shared__ float red[256];
    float m = -1e30f;
    for (int t = tid; t < 4096; t += 256) m = fmaxf(m, f2[t]);
    red[tid] = m;
    __syncthreads();
    for (int off = 128; off > 0; off >>= 1) {
        if (tid < off) red[tid] = fmaxf(red[tid], red[tid + off]);
        __syncthreads();
    }
    float M2 = red[0];
    if (tid == 0) M2out[z] = M2;
    for (int p = tid; p < 2048; p += 256) {
        float a0 = f2[2 * p] - M2, a1 = f2[2 * p + 1] - M2;
        uint2 q;
        q.x = pkrtz(exp2f(L2E * a0), exp2f(L2E * a1));
        q.y = pkrtz(exp2f(0.2f * L2E * a0), exp2f(0.2f * L2E * a1));
        pn[p] = q;
    }
}

// ---------------- fp16 MFMA masked-softmax attention — register-direct A-frags ----------
// Each wave owns 16 rows. Lane (l16,kq) computes P[row=l16][j=kt*32+kq*8+0..7] as packed
// fp16 DIRECTLY in the MFMA A-fragment layout: no Ps LDS, no per-tile barriers.
// w = max(Pp'*pn.x, Nn'*pn.y), Pp'=e^{min(0,.8t0)}, Nn'=e^{-max(0,.8t0)} (exact lrelu-exp).
// Z via ones-column MFMA. Writes unnormalized f32 partials + Z (shared row-max -> additive).
template <int FOUT>
__device__ __forceinline__ void attn_body(const _Float16* __restrict__ wt,
                                          const float* __restrict__ f1p,
                                          const uint2* __restrict__ pnp, float M2,
                                          const unsigned* __restrict__ mask32,
                                          float* __restrict__ part, float* __restrict__ Zb,
                                          int i0, int jlo, int nt,
                                          unsigned long long* lut) {
    constexpr int NN = 4096, TJ = 128;
    constexpr int NF = FOUT / 16;
    const int tid = threadIdx.x, lane = tid & 63, wv = tid >> 6;
    const int l16 = lane & 15, kq = lane >> 4;

    if (tid < 16) {
        unsigned lo = ((tid & 1) ? 0xFFFFu : 0u) | ((tid & 2) ? 0xFFFF0000u : 0u);
        unsigned hi = ((tid & 4) ? 0xFFFFu : 0u) | ((tid & 8) ? 0xFFFF0000u : 0u);
        lut[tid] = (unsigned long long)lo | ((unsigned long long)hi << 32);
    }
    __syncthreads();  // lut visible (only barrier in the kernel)

    const int row = wv * 16 + l16;            // this lane's P row (0..63 within block)
    const int i = i0 + row;
    float f1i = f1p[i];
    float t8 = 0.8f * (f1i + M2);
    unsigned Pp2, Nn2;
    {
        float Ppf = exp2f(L2E * fminf(0.f, t8));
        float Nnf = exp2f(-L2E * fmaxf(0.f, t8));
        Pp2 = pkrtz(Ppf, Ppf);
        Nn2 = pkrtz(Nnf, Nnf);
    }
    half8v ones;
#pragma unroll
    for (int k = 0; k < 8; ++k) ones[k] = (_Float16)1.0f;

    float4v acc[NF], accz;
    accz = (float4v){0.f, 0.f, 0.f, 0.f};
#pragma unroll
    for (int nf = 0; nf < NF; ++nf) acc[nf] = (float4v){0.f, 0.f, 0.f, 0.f};

    const uint4* mrow = (const uint4*)(mask32 + (size_t)i * (NN >> 5) + (jlo >> 5));

    for (int t = 0; t < nt; ++t) {
        int jt = jlo + t * TJ;
        uint4 mword = mrow[t];                // this row's 128 mask bits
        unsigned mws[4] = {mword.x, mword.y, mword.z, mword.w};
#pragma unroll
        for (int kt = 0; kt < 4; ++kt) {
            unsigned m8 = (mws[kt] >> (kq * 8)) & 0xff;
            const uint2* pw = pnp + ((jt + kt * 32 + kq * 8) >> 1);
            uint4 qa = *(const uint4*)pw;         // pairs 0,1
            uint4 qb = *(const uint4*)(pw + 2);   // pairs 2,3
            unsigned long long m0 = lut[m8 & 15];
            unsigned long long m1 = lut[m8 >> 4];
            uint4 w4;
            w4.x = pkmax(pkmul(Pp2, qa.x), pkmul(Nn2, qa.y)) & (unsigned)m0;
            w4.y = pkmax(pkmul(Pp2, qa.z), pkmul(Nn2, qa.w)) & (unsigned)(m0 >> 32);
            w4.z = pkmax(pkmul(Pp2, qb.x), pkmul(Nn2, qb.y)) & (unsigned)m1;
            w4.w = pkmax(pkmul(Pp2, qb.z), pkmul(Nn2, qb.w)) & (unsigned)(m1 >> 32);
            half8v afr = __builtin_bit_cast(half8v, w4);
            half8v bfr[NF];
#pragma unroll
            for (int nf = 0; nf < NF; ++nf)
                bfr[nf] = *(const half8v*)(wt + (size_t)(nf * 16 + l16) * NN +
                                           jt + kt * 32 + kq * 8);
            accz = __builtin_amdgcn_mfma_f32_16x16x32_f16(afr, ones, accz, 0, 0, 0);
#pragma unroll
            for (int nf = 0; nf < NF; ++nf)
                acc[nf] = __builtin_amdgcn_mfma_f32_16x16x32_f16(afr, bfr[nf], acc[nf],
                                                                 0, 0, 0);
        }
    }

    // D layout: col = l16, row_local = kq*4 + e
#pragma unroll
    for (int nf = 0; nf < NF; ++nf) {
        int rb = i0 + wv * 16 + kq * 4;
#pragma unroll
        for (int e = 0; e < 4; ++e)
            part[(size_t)(rb + e) * FOUT + nf * 16 + l16] = acc[nf][e];
    }
    if (l16 == 0) {
        int rb = i0 + wv * 16 + kq * 4;
#pragma unroll
        for (int e = 0; e < 4; ++e) Zb[rb + e] = accz[e];
    }
}

__global__ __launch_bounds__(256) void attnh_k(const _Float16* __restrict__ WhT,
                                               const float* __restrict__ f1h,
                                               const uint2* __restrict__ pnh,
                                               const float* __restrict__ M2,
                                               const unsigned* __restrict__ mask32,
                                               float* __restrict__ parth,
                                               float* __restrict__ Zh) {
    __shared__ unsigned long long lut[16];
    int head = blockIdx.y, chunk = blockIdx.z, slot = chunk * 8 + head;
    attn_body<64>(WhT + (size_t)head * 64 * 4096, f1h + (size_t)head * 4096,
                  pnh + (size_t)head * 2048, M2[head], mask32,
                  parth + (size_t)slot * 4096 * 64, Zh + (size_t)slot * 4096,
                  blockIdx.x * 64, chunk * 2048, 16, lut);
}

__global__ __launch_bounds__(256) void attno_k(const _Float16* __restrict__ Wh12T,
                                               const float* __restrict__ f1o,
                                               const uint2* __restrict__ pno,
                                               const float* __restrict__ M2,
                                               const unsigned* __restrict__ mask32,
                                               float* __restrict__ part2,
                                               float* __restrict__ Z2,
                                               float* __restrict__ part1,
                                               float* __restrict__ Z1) {
    __shared__ unsigned long long lut[16];
    int chunk = blockIdx.z;
    if (blockIdx.y == 0)
        attn_body<64>(Wh12T, f1o, pno, M2[8], mask32, part2 + (size_t)chunk * 4096 * 64,
                      Z2 + (size_t)chunk * 4096, blockIdx.x * 64, chunk * 512, 4, lut);
    else
        attn_body<16>(Wh12T + (size_t)64 * 4096, f1o + 4096, pno + 2048, M2[9], mask32,
                      part1 + (size_t)chunk * 4096 * 16, Z1 + (size_t)chunk * 4096,
                      blockIdx.x * 64, chunk * 512, 4, lut);
}

// ---------------- combine head-pass partials (2 chunks x 8 heads) -> bf16 hc ----------------
__global__ __launch_bounds__(256) void combH_k(const float* __restrict__ part,
                                               const float* __restrict__ Zp,
                                               unsigned short* __restrict__ hcb, int N) {
    int id = blockIdx.x * 256 + threadIdx.x;  // N*512
    int i = id >> 9, hf = id & 511;
    int h = hf >> 6, f = hf & 63;
    float s = 0.f, Z = 0.f;
#pragma unroll
    for (int c = 0; c < 2; c++) {
        int slot = c * 8 + h;
        s += part[((size_t)slot * N + i) * 64 + f];
        Z += Zp[(size_t)slot * N + i];
    }
    float o = s / Z;
    o = (o > 0.f) ? o : (__expf(o) - 1.f);
    hcb[id] = (unsigned short)(pkbf(o, 0.f) & 0xffff);
}

// ---------------- combine out2 partials (8) + residual (origT fp16) ----------------
__global__ __launch_bounds__(256) void comb2_k(const float* __restrict__ part,
                                               const float* __restrict__ Zp,
                                               const _Float16* __restrict__ origT,
                                               const float* __restrict__ bdown,
                                               float* __restrict__ zout,
                                               unsigned short* __restrict__ zb, int N) {
    int id = blockIdx.x * 256 + threadIdx.x;  // N*64
    int i = id >> 6, f = id & 63;
    float Zs = 0.f, s = 0.f;
#pragma unroll
    for (int c = 0; c < 8; c++) Zs += Zp[(size_t)c * N + i];
#pragma unroll
    for (int c = 0; c < 8; c++) s += part[((size_t)c * N + i) * 64 + f];
    float v = s / Zs + (float)origT[(size_t)f * N + i] + bdown[f];
    zout[id] = v;
    zb[id] = (unsigned short)(pkbf(v, 0.f) & 0xffff);
}

// ---------------- comb1 (8 chunks) + log_softmax + result2 ----------------
__global__ __launch_bounds__(256) void c1fin_k(const float* __restrict__ part1,
                                               const float* __restrict__ Z1,
                                               const float* __restrict__ zbuf,
                                               const float* __restrict__ wd,
                                               const float* __restrict__ bd,
                                               float* __restrict__ out, int N) {
    int i = blockIdx.x * 256 + threadIdx.x;
    float Z = 0.f;
#pragma unroll
    for (int c = 0; c < 8; c++) Z += Z1[(size_t)c * N + i];
    float v[16];
    float m = -1e30f;
#pragma unroll
    for (int f = 0; f < 16; f++) {
        float s = 0.f;
#pragma unroll
        for (int c = 0; c < 8; c++) s += part1[((size_t)c * N + i) * 16 + f];
        float o = s / Z;
        o = (o > 0.f) ? o : (expf(o) - 1.f);
        v[f] = o;
        m = fmaxf(m, o);
    }
    float se = 0.f;
#pragma unroll
    for (int f = 0; f < 16; f++) se += expf(v[f] - m);
    float l = m + logf(se);
#pragma unroll
    for (int f = 0; f < 16; f++) out[(size_t)i * 16 + f] = v[f] - l;
    float s2 = bd[0];
#pragma unroll
    for (int k = 0; k < 64; k++) s2 = fmaf(zbuf[(size_t)i * 64 + k], wd[k], s2);
    out[(size_t)N * 16 + i] = s2;
}

extern "C" void kernel_launch(void* const* d_in, const int* in_sizes, int n_in,
                              void* d_out, int out_size, void* d_ws, size_t ws_size,
                              hipStream_t stream) {
    const float* x = (const float*)d_in[0];
    const int* adj = (const int*)d_in[1];
    const float* W_att = (const float*)d_in[2];
    const float* a_att = (const float*)d_in[3];
    const float* W_out1 = (const float*)d_in[4];
    const float* a_out1 = (const float*)d_in[5];
    const float* W_out2 = (const float*)d_in[6];
    const float* a_out2 = (const float*)d_in[7];
    const float* W_down = (const float*)d_in[8];
    const float* b_down = (const float*)d_in[9];
    const float* w_deg = (const float*)d_in[10];
    const float* b_deg = (const float*)d_in[11];
    const float* W_deg3 = (const float*)d_in[12];
    const float* b_deg3 = (const float*)d_in[13];
    float* out = (float*)d_out;

    constexpr int N = 4096, NF = 512, NH = 64, NC = 16, H = 8, DM = 128;

    char* wp = (char*)d_ws;
    auto alloc = [&](size_t b) {
        char* p = wp;
        wp += (b + 255) & ~(size_t)255;
        return p;
    };
    unsigned long long* mask = (unsigned long long*)alloc((size_t)N * N / 8);
    unsigned short* xb = (unsigned short*)alloc((size_t)N * NF * 2);
    unsigned short* WT = (unsigned short*)alloc((size_t)656 * NF * 2);   // 10x64 + 16 rows
    unsigned short* Wd3T = (unsigned short*)alloc((size_t)DM * NH * 2);
    unsigned short* WhT = (unsigned short*)alloc((size_t)9 * NH * N * 2);  // 8 heads + origT
    float* f1h = (float*)alloc((size_t)H * N * 4);
    float* f2h = (float*)alloc((size_t)H * N * 4);
    uint2* pnh = (uint2*)alloc((size_t)H * 2048 * 8);
    float* M2 = (float*)alloc(256);
    float* parth = (float*)alloc((size_t)16 * N * NH * 4);   // 16 slots; later aliased
    float* Zh = (float*)alloc((size_t)16 * N * 4);
    unsigned short* hcb = (unsigned short*)alloc((size_t)N * NF * 2);
    unsigned short* Wh12T = (unsigned short*)alloc((size_t)80 * N * 2);
    float* f1o = (float*)alloc((size_t)2 * N * 4);
    float* f2o = (float*)alloc((size_t)2 * N * 4);
    uint2* pno = (uint2*)alloc((size_t)2 * 2048 * 8);
    float* zbuf = (float*)alloc((size_t)N * NH * 4);
    unsigned short* zb = (unsigned short*)alloc((size_t)N * NH * 2);

    // alias: attno partials reuse parth/Zh (consumed by combH before attno runs)
    float* part2 = parth;                                  // 8 slots x N x 64
    float* part1 = parth + (size_t)8 * N * NH;             // 8 slots x N x 16
    float* Z2 = Zh;                                        // 8 x N
    float* Z1 = Zh + (size_t)8 * N;                        // 8 x N

    const unsigned* mask32 = (const unsigned*)mask;

    // 1. prep: pack mask + x->bf16 + all weight transposes (one region dispatch)
    prep_k<<<66896, 256, 0, stream>>>(adj, mask, x, xb, W_att, W_down, W_out2, W_out1,
                                      W_deg3, WT, Wd3T);
    // 2. 9-slice batched GEMM: WhT[0..7] = (xb@W_att[h])^T fp16, WhT[8] = origT
    gemmb_k<128, 32, 1><<<dim3(N / 128, 2, 9), 256, 0, stream>>>(
        (const __hip_bfloat16*)xb, (const __hip_bfloat16*)WT, nullptr, WhT, N, NH, NF);
    // 3. f1/f2 per head; max+pn tables
    fvh_k<<<dim3(16, H), 256, 0, stream>>>((const _Float16*)WhT, a_att, f1h, f2h);
    rmaxpn_k<<<H, 256, 0, stream>>>(f2h, M2, pnh);
    // 4. 8-head fp16 MFMA attention (register-direct, barrier-free; 2-way j-split)
    attnh_k<<<dim3(N / 64, H, 2), 256, 0, stream>>>((const _Float16*)WhT, f1h, pnh, M2,
                                                    mask32, parth, Zh);
    combH_k<<<(size_t)N * 512 / 256, 256, 0, stream>>>(parth, Zh, hcb, N);
    // 5. fused out-projection GEMM (80 stacked cols) + f-vectors + max/pn
    gemmb_k<64, 16, 1><<<dim3(N / 64, 5, 1), 256, 0, stream>>>(
        (const __hip_bfloat16*)hcb, (const __hip_bfloat16*)(WT + (size_t)9 * NH * NF),
        nullptr, Wh12T, N, 80, NF);
    fvo_k<<<dim3(16, 2), 256, 0, stream>>>((const _Float16*)Wh12T, a_out2, a_out1, f1o, f2o);
    rmaxpn_k<<<2, 256, 0, stream>>>(f2o, M2 + 8, pno);
    // 6. fused out2/out1 attention (8-way j-split)
    attno_k<<<dim3(N / 64, 2, 8), 256, 0, stream>>>((const _Float16*)Wh12T, f1o, pno, M2,
                                                    mask32, part2, Z2, part1, Z1);
    comb2_k<<<(size_t)N * 64 / 256, 256, 0, stream>>>(
        part2, Z2, (const _Float16*)(WhT + (size_t)8 * NH * N), b_down, zbuf, zb, N);
    // 7. outputs
    c1fin_k<<<N / 256, 256, 0, stream>>>(part1, Z1, zbuf, w_deg, b_deg, out, N);
    gemmb_k<64, 64, 0><<<dim3(N / 64, DM / 64, 1), 256, 0, stream>>>(
        (const __hip_bfloat16*)zb, (const __hip_bfloat16*)Wd3T, b_deg3,
        out + (size_t)N * NC + N, N, DM, NH);
}

// Round 9
// 274.600 us; speedup vs baseline: 1.4373x; 1.4373x over previous
//
#include <hip/hip_runtime.h>
#include <hip/hip_bf16.h>

#define L2E 1.44269504088896f

typedef __attribute__((ext_vector_type(8))) short short8v;
typedef __attribute__((ext_vector_type(8))) _Float16 half8v;
typedef __attribute__((ext_vector_type(4))) float float4v;

__device__ __forceinline__ void gld16(void* lds, const void* gp) {
    __builtin_amdgcn_global_load_lds(
        (const __attribute__((address_space(1))) unsigned int*)gp,
        (__attribute__((address_space(3))) unsigned int*)lds, 16, 0, 0);
}
__device__ __forceinline__ unsigned pkbf(float a, float b) {
    unsigned r;
    asm("v_cvt_pk_bf16_f32 %0, %1, %2" : "=v"(r) : "v"(a), "v"(b));
    return r;
}
__device__ __forceinline__ unsigned pkrtz(float a, float b) {
    unsigned r;
    asm("v_cvt_pkrtz_f16_f32 %0, %1, %2" : "=v"(r) : "v"(a), "v"(b));
    return r;
}
__device__ __forceinline__ unsigned pkmul(unsigned a, unsigned b) {
    unsigned r;
    asm("v_pk_mul_f16 %0, %1, %2" : "=v"(r) : "v"(a), "v"(b));
    return r;
}
__device__ __forceinline__ unsigned pkmax(unsigned a, unsigned b) {
    unsigned r;
    asm("v_pk_max_f16 %0, %1, %2" : "=v"(r) : "v"(a), "v"(b));
    return r;
}
__device__ __forceinline__ unsigned pkadd(unsigned a, unsigned b) {
    unsigned r;
    asm("v_pk_add_f16 %0, %1, %2" : "=v"(r) : "v"(a), "v"(b));
    return r;
}

// ---------------- prep: pack adj, cvt x->bf16, all weight transposes ----------------
__device__ __forceinline__ void tp_body(const float* __restrict__ src,
                                        unsigned short* __restrict__ dst,
                                        int M, int F, int j0, int f0, float (*t)[17]) {
    int tid = threadIdx.x;
    int rr = tid >> 2, c0 = (tid & 3) * 4;
    float4 v = *(const float4*)&src[(size_t)(j0 + rr) * F + f0 + c0];
    t[rr][c0 + 0] = v.x;
    t[rr][c0 + 1] = v.y;
    t[rr][c0 + 2] = v.z;
    t[rr][c0 + 3] = v.w;
    __syncthreads();
    int f = tid >> 4, jl = (tid & 15) * 4;
    ushort4 o;
    o.x = (unsigned short)(pkbf(t[jl + 0][f], 0.f) & 0xffff);
    o.y = (unsigned short)(pkbf(t[jl + 1][f], 0.f) & 0xffff);
    o.z = (unsigned short)(pkbf(t[jl + 2][f], 0.f) & 0xffff);
    o.w = (unsigned short)(pkbf(t[jl + 3][f], 0.f) & 0xffff);
    *(ushort4*)&dst[(size_t)(f0 + f) * M + j0 + jl] = o;
}

__global__ __launch_bounds__(256) void prep_k(const int* __restrict__ adj,
                                              unsigned long long* __restrict__ mask,
                                              const float* __restrict__ x,
                                              unsigned short* __restrict__ xb,
                                              const float* __restrict__ W_att,
                                              const float* __restrict__ W_down,
                                              const float* __restrict__ W_out2,
                                              const float* __restrict__ W_out1,
                                              const float* __restrict__ W_deg3,
                                              unsigned short* __restrict__ WT,
                                              unsigned short* __restrict__ Wd3T) {
    __shared__ float tbuf[64][17];
    int bx = blockIdx.x, tid = threadIdx.x;
    if (bx < 65536) {                                   // pack adj bitmask
        size_t idx = (size_t)bx * 256 + tid;
        unsigned long long b = __ballot(adj[idx] > 0);
        if ((tid & 63) == 0) mask[idx >> 6] = b;
    } else if (bx < 66560) {                            // x -> bf16
        int i = (bx - 65536) * 256 + tid;
        float4 a = ((const float4*)x)[i * 2];
        float4 b = ((const float4*)x)[i * 2 + 1];
        uint4 o = {pkbf(a.x, a.y), pkbf(a.z, a.w), pkbf(b.x, b.y), pkbf(b.z, b.w)};
        ((uint4*)xb)[i] = o;
    } else if (bx < 66880) {                            // W_att/W_down/W_out2 -> WT[0..9]
        int r = bx - 66560;
        int z = r >> 5, rr = r & 31;
        const float* src = (z < 8) ? W_att + (size_t)z * 512 * 64 : ((z == 8) ? W_down : W_out2);
        tp_body(src, WT + (size_t)z * 64 * 512, 512, 64, (rr & 7) * 64, (rr >> 3) * 16, tbuf);
    } else if (bx < 66888) {                            // W_out1 -> WT rows 640..655
        int r = bx - 66880;
        tp_body(W_out1, WT + (size_t)640 * 512, 512, 16, r * 64, 0, tbuf);
    } else {                                            // W_deg3 [64][128] -> Wd3T [128][64]
        int r = bx - 66888;
        tp_body(W_deg3, Wd3T, 64, 128, 0, r * 16, tbuf);
    }
}

// ---------------- bf16 MFMA GEMM: C = A[MxK] @ Bt[NxK]^T ----------------
// OUTMODE 0: C f32 [Z][M][N] (+bias);  OUTMODE 1: C fp16 [Z][N][M] (transposed)
template <int BM, int BN, int OUTMODE>
__global__ __launch_bounds__(256) void gemmb_k(const __hip_bfloat16* __restrict__ A,
                                               const __hip_bfloat16* __restrict__ BtB,
                                               const float* __restrict__ bias,
                                               void* __restrict__ CB,
                                               int M, int N, int K) {
    constexpr int BK = 64;
    constexpr int MF = BM / 64;                      // row-frags per wave
    const int tid = threadIdx.x, lane = tid & 63, wv = tid >> 6;
    const int l16 = lane & 15, kq = lane >> 4;
    const int row0 = blockIdx.x * BM, col0 = blockIdx.y * BN;
    const size_t czs = (size_t)M * N;
    const __hip_bfloat16* Bt = BtB + (size_t)blockIdx.z * N * K;

    __shared__ __align__(16) __hip_bfloat16 As[2][BM][BK];

    auto stageA = [&](int k0, int b) {
#pragma unroll
        for (int c = 0; c < BM / 32; ++c) {
            int off = (tid + c * 256) * 16;
            int rr = off >> 7;
            int ch = (off >> 4) & 7;
            int chs = ch ^ (rr & 7);
            gld16((char*)&As[b][0][0] + off, A + (size_t)(row0 + rr) * K + k0 + chs * 8);
        }
    };

    float4v acc[MF][BN / 16];
#pragma unroll
    for (int mf = 0; mf < MF; ++mf)
#pragma unroll
        for (int nf = 0; nf < BN / 16; ++nf) acc[mf][nf] = (float4v){0.f, 0.f, 0.f, 0.f};

    const int rowb = wv * (BM / 4);
    const int nk = K / BK;
    stageA(0, 0);
    for (int t = 0; t < nk; ++t) {
        int k0 = t * BK, cur = t & 1;
        if (t + 1 < nk) stageA(k0 + BK, cur ^ 1);
        short8v bfr[BN / 16][2];
#pragma unroll
        for (int nf = 0; nf < BN / 16; ++nf)
#pragma unroll
            for (int ks = 0; ks < 2; ++ks)
                bfr[nf][ks] = *(const short8v*)(Bt + (size_t)(col0 + nf * 16 + l16) * K +
                                                k0 + ks * 32 + kq * 8);
        __syncthreads();
        const char* asb = (const char*)&As[cur][0][0];
#pragma unroll
        for (int ks = 0; ks < 2; ++ks) {
            short8v afr[MF];
#pragma unroll
            for (int mf = 0; mf < MF; ++mf) {
                int rr = rowb + mf * 16 + l16;
                afr[mf] = *(const short8v*)(asb + rr * 128 +
                                            ((ks * 64 + kq * 16) ^ ((rr & 7) << 4)));
            }
#pragma unroll
            for (int mf = 0; mf < MF; ++mf)
#pragma unroll
                for (int nf = 0; nf < BN / 16; ++nf)
                    acc[mf][nf] = __builtin_amdgcn_mfma_f32_16x16x32_bf16(
                        afr[mf], bfr[nf][ks], acc[mf][nf], 0, 0, 0);
        }
        __syncthreads();
    }

#pragma unroll
    for (int mf = 0; mf < MF; ++mf)
#pragma unroll
        for (int nf = 0; nf < BN / 16; ++nf) {
            int rb = row0 + rowb + mf * 16 + kq * 4;
            int col = col0 + nf * 16 + l16;
            if constexpr (OUTMODE == 0) {
                float bb = bias ? bias[col] : 0.f;
                float* C = (float*)CB + (size_t)blockIdx.z * czs;
#pragma unroll
                for (int e = 0; e < 4; ++e) C[(size_t)(rb + e) * N + col] = acc[mf][nf][e] + bb;
            } else {
                uint2 u = {pkrtz(acc[mf][nf][0], acc[mf][nf][1]),
                           pkrtz(acc[mf][nf][2], acc[mf][nf][3])};
                unsigned short* Ct = (unsigned short*)CB + (size_t)blockIdx.z * czs;
                *(uint2*)&Ct[(size_t)col * M + rb] = u;
            }
        }
}

// ---------------- f1/f2 from fp16 WhT (coalesced) ----------------
__global__ __launch_bounds__(256) void fvh_k(const _Float16* __restrict__ WhT,
                                             const float* __restrict__ a,
                                             float* __restrict__ f1, float* __restrict__ f2) {
    int zz = blockIdx.y;
    const _Float16* W = WhT + (size_t)zz * 64 * 4096;
    const float* az = a + (size_t)zz * 128;
    int i = blockIdx.x * 256 + threadIdx.x;
    float s1 = 0.f, s2 = 0.f;
    for (int k = 0; k < 64; k++) {
        float ww = (float)W[(size_t)k * 4096 + i];
        s1 = fmaf(ww, az[k], s1);
        s2 = fmaf(ww, az[64 + k], s2);
    }
    f1[(size_t)zz * 4096 + i] = s1;
    f2[(size_t)zz * 4096 + i] = s2;
}

__global__ __launch_bounds__(256) void fvo_k(const _Float16* __restrict__ Wh12T,
                                             const float* __restrict__ a2,
                                             const float* __restrict__ a1,
                                             float* __restrict__ f1o, float* __restrict__ f2o) {
    int y = blockIdx.y;
    const _Float16* W = Wh12T + (y ? (size_t)64 * 4096 : 0);
    const float* a = y ? a1 : a2;
    int D = y ? 16 : 64;
    int i = blockIdx.x * 256 + threadIdx.x;
    float s1 = 0.f, s2 = 0.f;
    for (int k = 0; k < D; k++) {
        float ww = (float)W[(size_t)k * 4096 + i];
        s1 = fmaf(ww, a[k], s1);
        s2 = fmaf(ww, a[D + k], s2);
    }
    f1o[(size_t)y * 4096 + i] = s1;
    f2o[(size_t)y * 4096 + i] = s2;
}

// ---------------- per-batch max of f2 + fp16 pn pair-table ----------------
__global__ __launch_bounds__(256) void rmaxpn_k(const float* __restrict__ f2B,
                                                float* __restrict__ M2out,
                                                uint2* __restrict__ pnB) {
    int z = blockIdx.x, tid = threadIdx.x;
    const float* f2 = f2B + (size_t)z * 4096;
    uint2* pn = pnB + (size_t)z * 2048;
    __shared__ float red[256];
    float m = -1e30f;
    for (int t = tid; t < 4096; t += 256) m = fmaxf(m, f2[t]);
    red[tid] = m;
    __syncthreads();
    for (int off = 128; off > 0; off >>= 1) {
        if (tid < off) red[tid] = fmaxf(red[tid], red[tid + off]);
        __syncthreads();
    }
    float M2 = red[0];
    if (tid == 0) M2out[z] = M2;
    for (int p = tid; p < 2048; p += 256) {
        float a0 = f2[2 * p] - M2, a1 = f2[2 * p + 1] - M2;
        uint2 q;
        q.x = pkrtz(exp2f(L2E * a0), exp2f(L2E * a1));
        q.y = pkrtz(exp2f(0.2f * L2E * a0), exp2f(0.2f * L2E * a1));
        pn[p] = q;
    }
}

// ---------------- fp16 MFMA masked-softmax attention (LDS-staged B) ----------------
// P on VALU (w = max(Pp'*pn.x, Nn'*pn.y), exact lrelu-exp identity, factors <=1 fp16-safe),
// packed into padded-row Ps (272B rows, conflict-free, no XOR). B tile [FOUT][128] staged
// into LDS via global_load_lds (XOR-swizzled source, shared by all 4 waves -> 1/4 L1
// traffic vs per-wave gather). Z on VALU via v_pk_add_f16 + f32 accumulate (no Z-MFMA).
// Writes unnormalized f32 partials + Z (shared row-max -> additive combine).
template <int FOUT>
__device__ __forceinline__ void attn_body(const _Float16* __restrict__ wt,
                                          const float* __restrict__ f1p,
                                          const uint2* __restrict__ pnp, float M2,
                                          const unsigned* __restrict__ mask32,
                                          float* __restrict__ part, float* __restrict__ Zb,
                                          int i0, int jlo, int nt,
                                          char* __restrict__ bsbase,
                                          char* __restrict__ psbase,
                                          unsigned long long* lut, float (*Zs)[4]) {
    constexpr int NN = 4096, TJ = 128, PROW = 272;     // Ps row pitch (17*16B)
    constexpr int MF = (FOUT == 64) ? 2 : 1;
    constexpr int NF = (FOUT == 64) ? 2 : 1;
    constexpr int PW = (FOUT * TJ * 2) / 4096;         // gld16 calls per wave
    const int tid = threadIdx.x, lane = tid & 63, wv = tid >> 6;
    const int jg = __builtin_amdgcn_readfirstlane(wv);
    const int l16 = lane & 15, kq = lane >> 4, r = lane;

    if (tid < 16) {
        unsigned lo = ((tid & 1) ? 0xFFFFu : 0u) | ((tid & 2) ? 0xFFFF0000u : 0u);
        unsigned hi = ((tid & 4) ? 0xFFFFu : 0u) | ((tid & 8) ? 0xFFFF0000u : 0u);
        lut[tid] = (unsigned long long)lo | ((unsigned long long)hi << 32);
    }

    float f1i = f1p[i0 + r];
    float t8 = 0.8f * (f1i + M2);
    unsigned Pp2, Nn2;
    {
        float Ppf = exp2f(L2E * fminf(0.f, t8));
        float Nnf = exp2f(-L2E * fmaxf(0.f, t8));
        Pp2 = pkrtz(Ppf, Ppf);
        Nn2 = pkrtz(Nnf, Nnf);
    }
    float Z = 0.f;

    float4v acc[MF][NF];
#pragma unroll
    for (int mf = 0; mf < MF; ++mf)
#pragma unroll
        for (int nf = 0; nf < NF; ++nf) acc[mf][nf] = (float4v){0.f, 0.f, 0.f, 0.f};

    const int rowb = (FOUT == 64) ? (wv & 1) * 32 : wv * 16;
    const int colb = (FOUT == 64) ? (wv >> 1) * 32 : 0;
    const unsigned* mrowp = mask32 + (size_t)(i0 + r) * (NN >> 5) + (jlo >> 5) + jg;

    auto stage = [&](int jt) {
#pragma unroll
        for (int c = 0; c < PW; ++c) {
            int q = wv * PW + c;
            int rr = q * 4 + kq;                       // B row within tile
            int ch = l16;                              // 16B chunk within 256B row
            int chs = (ch & 8) | ((ch & 7) ^ (rr & 7));  // inverse-swizzled SOURCE
            gld16(bsbase + q * 1024, wt + (size_t)rr * NN + jt + chs * 8);
        }
    };

    auto pcompute = [&](int jt, unsigned mw) {
        const uint2* pw = pnp + (jt >> 1) + jg * 16;   // wave-uniform -> s_load
        char* pd = psbase + r * PROW + jg * 64;
#pragma unroll
        for (int b = 0; b < 4; ++b) {
            unsigned long long m0 = lut[(mw >> (b * 8)) & 15];
            unsigned long long m1 = lut[(mw >> (b * 8 + 4)) & 15];
            uint2 q0 = pw[b * 4 + 0], q1 = pw[b * 4 + 1];
            uint2 q2 = pw[b * 4 + 2], q3 = pw[b * 4 + 3];
            uint4 w4;
            w4.x = pkmax(pkmul(Pp2, q0.x), pkmul(Nn2, q0.y)) & (unsigned)m0;
            w4.y = pkmax(pkmul(Pp2, q1.x), pkmul(Nn2, q1.y)) & (unsigned)(m0 >> 32);
            w4.z = pkmax(pkmul(Pp2, q2.x), pkmul(Nn2, q2.y)) & (unsigned)m1;
            w4.w = pkmax(pkmul(Pp2, q3.x), pkmul(Nn2, q3.y)) & (unsigned)(m1 >> 32);
            *(uint4*)(pd + b * 16) = w4;
            unsigned s = pkadd(pkadd(w4.x, w4.y), pkadd(w4.z, w4.w));
            float lo, hi;
            asm("v_cvt_f32_f16 %0, %1" : "=v"(lo) : "v"(s));
            asm("v_cvt_f32_f16 %0, %1" : "=v"(hi) : "v"(s >> 16));
            Z += lo + hi;
        }
    };

    stage(jlo);
    __syncthreads();                                   // lut visible, Bs(0) drained
    pcompute(jlo, mrowp[0]);

    for (int t = 0; t < nt; ++t) {
        int jt = jlo + t * TJ;
        __syncthreads();                               // Ps(t) + Bs(t) ready
        half8v bfr[4][NF];
#pragma unroll
        for (int kt = 0; kt < 4; ++kt)
#pragma unroll
            for (int nf = 0; nf < NF; ++nf) {
                int col = colb + nf * 16 + l16;
                int cc = kt * 4 + kq;
                int ccs = (cc & 8) | ((cc & 7) ^ (col & 7));
                bfr[kt][nf] = *(const half8v*)(bsbase + col * 256 + ccs * 16);
            }
#pragma unroll
        for (int kt = 0; kt < 4; ++kt) {
            half8v afr[MF];
#pragma unroll
            for (int mf = 0; mf < MF; ++mf) {
                int row = rowb + mf * 16 + l16;
                afr[mf] = *(const half8v*)(psbase + row * PROW + kt * 64 + kq * 16);
            }
#pragma unroll
            for (int mf = 0; mf < MF; ++mf)
#pragma unroll
                for (int nf = 0; nf < NF; ++nf)
                    acc[mf][nf] = __builtin_amdgcn_mfma_f32_16x16x32_f16(
                        afr[mf], bfr[kt][nf], acc[mf][nf], 0, 0, 0);
        }
        __syncthreads();                               // reads done before overwrite
        if (t + 1 < nt) {
            stage(jt + TJ);                            // async, drains at next barrier
            pcompute(jt + TJ, mrowp[(t + 1) * 4]);     // VALU covers load latency
        }
    }

    Zs[r][wv] = Z;
    __syncthreads();
    if (tid < 64) Zb[i0 + tid] = Zs[tid][0] + Zs[tid][1] + Zs[tid][2] + Zs[tid][3];

#pragma unroll
    for (int mf = 0; mf < MF; ++mf)
#pragma unroll
        for (int nf = 0; nf < NF; ++nf) {
            int rbl = rowb + mf * 16 + kq * 4;
            int col = colb + nf * 16 + l16;
#pragma unroll
            for (int e = 0; e < 4; ++e)
                part[(size_t)(i0 + rbl + e) * FOUT + col] = acc[mf][nf][e];
        }
}

__global__ __launch_bounds__(256, 4) void attnh_k(const _Float16* __restrict__ WhT,
                                                  const float* __restrict__ f1h,
                                                  const uint2* __restrict__ pnh,
                                                  const float* __restrict__ M2,
                                                  const unsigned* __restrict__ mask32,
                                                  float* __restrict__ parth,
                                                  float* __restrict__ Zh) {
    __shared__ __align__(16) char Bs[64 * 256];
    __shared__ __align__(16) char Ps[64 * 272];
    __shared__ unsigned long long lut[16];
    __shared__ float Zs[64][4];
    int head = blockIdx.y, chunk = blockIdx.z, slot = chunk * 8 + head;
    attn_body<64>(WhT + (size_t)head * 64 * 4096, f1h + (size_t)head * 4096,
                  pnh + (size_t)head * 2048, M2[head], mask32,
                  parth + (size_t)slot * 4096 * 64, Zh + (size_t)slot * 4096,
                  blockIdx.x * 64, chunk * 2048, 16, Bs, Ps, lut, Zs);
}

__global__ __launch_bounds__(256, 4) void attno_k(const _Float16* __restrict__ Wh12T,
                                                  const float* __restrict__ f1o,
                                                  const uint2* __restrict__ pno,
                                                  const float* __restrict__ M2,
                                                  const unsigned* __restrict__ mask32,
                                                  float* __restrict__ part2,
                                                  float* __restrict__ Z2,
                                                  float* __restrict__ part1,
                                                  float* __restrict__ Z1) {
    __shared__ __align__(16) char Bs[64 * 256];
    __shared__ __align__(16) char Ps[64 * 272];
    __shared__ unsigned long long lut[16];
    __shared__ float Zs[64][4];
    int chunk = blockIdx.z;
    if (blockIdx.y == 0)
        attn_body<64>(Wh12T, f1o, pno, M2[8], mask32, part2 + (size_t)chunk * 4096 * 64,
                      Z2 + (size_t)chunk * 4096, blockIdx.x * 64, chunk * 512, 4,
                      Bs, Ps, lut, Zs);
    else
        attn_body<16>(Wh12T + (size_t)64 * 4096, f1o + 4096, pno + 2048, M2[9], mask32,
                      part1 + (size_t)chunk * 4096 * 16, Z1 + (size_t)chunk * 4096,
                      blockIdx.x * 64, chunk * 512, 4, Bs, Ps, lut, Zs);
}

// ---------------- combine head-pass partials (2 chunks x 8 heads) -> bf16 hc ----------------
__global__ __launch_bounds__(256) void combH_k(const float* __restrict__ part,
                                               const float* __restrict__ Zp,
                                               unsigned short* __restrict__ hcb, int N) {
    int id = blockIdx.x * 256 + threadIdx.x;  // N*512
    int i = id >> 9, hf = id & 511;
    int h = hf >> 6, f = hf & 63;
    float s = 0.f, Z = 0.f;
#pragma unroll
    for (int c = 0; c < 2; c++) {
        int slot = c * 8 + h;
        s += part[((size_t)slot * N + i) * 64 + f];
        Z += Zp[(size_t)slot * N + i];
    }
    float o = s / Z;
    o = (o > 0.f) ? o : (__expf(o) - 1.f);
    hcb[id] = (unsigned short)(pkbf(o, 0.f) & 0xffff);
}

// ---------------- combine out2 partials (8) + residual (origT fp16) ----------------
__global__ __launch_bounds__(256) void comb2_k(const float* __restrict__ part,
                                               const float* __restrict__ Zp,
                                               const _Float16* __restrict__ origT,
                                               const float* __restrict__ bdown,
                                               float* __restrict__ zout,
                                               unsigned short* __restrict__ zb, int N) {
    int id = blockIdx.x * 256 + threadIdx.x;  // N*64
    int i = id >> 6, f = id & 63;
    float Zs = 0.f, s = 0.f;
#pragma unroll
    for (int c = 0; c < 8; c++) Zs += Zp[(size_t)c * N + i];
#pragma unroll
    for (int c = 0; c < 8; c++) s += part[((size_t)c * N + i) * 64 + f];
    float v = s / Zs + (float)origT[(size_t)f * N + i] + bdown[f];
    zout[id] = v;
    zb[id] = (unsigned short)(pkbf(v, 0.f) & 0xffff);
}

// ---------------- comb1 (8 chunks) + log_softmax + result2 ----------------
__global__ __launch_bounds__(256) void c1fin_k(const float* __restrict__ part1,
                                               const float* __restrict__ Z1,
                                               const float* __restrict__ zbuf,
                                               const float* __restrict__ wd,
                                               const float* __restrict__ bd,
                                               float* __restrict__ out, int N) {
    int i = blockIdx.x * 256 + threadIdx.x;
    float Z = 0.f;
#pragma unroll
    for (int c = 0; c < 8; c++) Z += Z1[(size_t)c * N + i];
    float v[16];
    float m = -1e30f;
#pragma unroll
    for (int f = 0; f < 16; f++) {
        float s = 0.f;
#pragma unroll
        for (int c = 0; c < 8; c++) s += part1[((size_t)c * N + i) * 16 + f];
        float o = s / Z;
        o = (o > 0.f) ? o : (expf(o) - 1.f);
        v[f] = o;
        m = fmaxf(m, o);
    }
    float se = 0.f;
#pragma unroll
    for (int f = 0; f < 16; f++) se += expf(v[f] - m);
    float l = m + logf(se);
#pragma unroll
    for (int f = 0; f < 16; f++) out[(size_t)i * 16 + f] = v[f] - l;
    float s2 = bd[0];
#pragma unroll
    for (int k = 0; k < 64; k++) s2 = fmaf(zbuf[(size_t)i * 64 + k], wd[k], s2);
    out[(size_t)N * 16 + i] = s2;
}

extern "C" void kernel_launch(void* const* d_in, const int* in_sizes, int n_in,
                              void* d_out, int out_size, void* d_ws, size_t ws_size,
                              hipStream_t stream) {
    const float* x = (const float*)d_in[0];
    const int* adj = (const int*)d_in[1];
    const float* W_att = (const float*)d_in[2];
    const float* a_att = (const float*)d_in[3];
    const float* W_out1 = (const float*)d_in[4];
    const float* a_out1 = (const float*)d_in[5];
    const float* W_out2 = (const float*)d_in[6];
    const float* a_out2 = (const float*)d_in[7];
    const float* W_down = (const float*)d_in[8];
    const float* b_down = (const float*)d_in[9];
    const float* w_deg = (const float*)d_in[10];
    const float* b_deg = (const float*)d_in[11];
    const float* W_deg3 = (const float*)d_in[12];
    const float* b_deg3 = (const float*)d_in[13];
    float* out = (float*)d_out;

    constexpr int N = 4096, NF = 512, NH = 64, NC = 16, H = 8, DM = 128;

    char* wp = (char*)d_ws;
    auto alloc = [&](size_t b) {
        char* p = wp;
        wp += (b + 255) & ~(size_t)255;
        return p;
    };
    unsigned long long* mask = (unsigned long long*)alloc((size_t)N * N / 8);
    unsigned short* xb = (unsigned short*)alloc((size_t)N * NF * 2);
    unsigned short* WT = (unsigned short*)alloc((size_t)656 * NF * 2);   // 10x64 + 16 rows
    unsigned short* Wd3T = (unsigned short*)alloc((size_t)DM * NH * 2);
    unsigned short* WhT = (unsigned short*)alloc((size_t)9 * NH * N * 2);  // 8 heads + origT
    float* f1h = (float*)alloc((size_t)H * N * 4);
    float* f2h = (float*)alloc((size_t)H * N * 4);
    uint2* pnh = (uint2*)alloc((size_t)H * 2048 * 8);
    float* M2 = (float*)alloc(256);
    float* parth = (float*)alloc((size_t)16 * N * NH * 4);   // 16 slots; later aliased
    float* Zh = (float*)alloc((size_t)16 * N * 4);
    unsigned short* hcb = (unsigned short*)alloc((size_t)N * NF * 2);
    unsigned short* Wh12T = (unsigned short*)alloc((size_t)80 * N * 2);
    float* f1o = (float*)alloc((size_t)2 * N * 4);
    float* f2o = (float*)alloc((size_t)2 * N * 4);
    uint2* pno = (uint2*)alloc((size_t)2 * 2048 * 8);
    float* zbuf = (float*)alloc((size_t)N * NH * 4);
    unsigned short* zb = (unsigned short*)alloc((size_t)N * NH * 2);

    // alias: attno partials reuse parth/Zh (consumed by combH before attno runs)
    float* part2 = parth;                                  // 8 slots x N x 64
    float* part1 = parth + (size_t)8 * N * NH;             // 8 slots x N x 16
    float* Z2 = Zh;                                        // 8 x N
    float* Z1 = Zh + (size_t)8 * N;                        // 8 x N

    const unsigned* mask32 = (const unsigned*)mask;

    // 1. prep: pack mask + x->bf16 + all weight transposes (one region dispatch)
    prep_k<<<66896, 256, 0, stream>>>(adj, mask, x, xb, W_att, W_down, W_out2, W_out1,
                                      W_deg3, WT, Wd3T);
    // 2. 9-slice batched GEMM: WhT[0..7] = (xb@W_att[h])^T fp16, WhT[8] = origT
    gemmb_k<128, 32, 1><<<dim3(N / 128, 2, 9), 256, 0, stream>>>(
        (const __hip_bfloat16*)xb, (const __hip_bfloat16*)WT, nullptr, WhT, N, NH, NF);
    // 3. f1/f2 per head; max+pn tables
    fvh_k<<<dim3(16, H), 256, 0, stream>>>((const _Float16*)WhT, a_att, f1h, f2h);
    rmaxpn_k<<<H, 256, 0, stream>>>(f2h, M2, pnh);
    // 4. 8-head fp16 MFMA attention (LDS-staged B, 2-way j-split) + combine
    attnh_k<<<dim3(N / 64, H, 2), 256, 0, stream>>>((const _Float16*)WhT, f1h, pnh, M2,
                                                    mask32, parth, Zh);
    combH_k<<<(size_t)N * 512 / 256, 256, 0, stream>>>(parth, Zh, hcb, N);
    // 5. fused out-projection GEMM (80 stacked cols) + f-vectors + max/pn
    gemmb_k<64, 16, 1><<<dim3(N / 64, 5, 1), 256, 0, stream>>>(
        (const __hip_bfloat16*)hcb, (const __hip_bfloat16*)(WT + (size_t)9 * NH * NF),
        nullptr, Wh12T, N, 80, NF);
    fvo_k<<<dim3(16, 2), 256, 0, stream>>>((const _Float16*)Wh12T, a_out2, a_out1, f1o, f2o);
    rmaxpn_k<<<2, 256, 0, stream>>>(f2o, M2 + 8, pno);
    // 6. fused out2/out1 attention (8-way j-split)
    attno_k<<<dim3(N / 64, 2, 8), 256, 0, stream>>>((const _Float16*)Wh12T, f1o, pno, M2,
                                                    mask32, part2, Z2, part1, Z1);
    comb2_k<<<(size_t)N * 64 / 256, 256, 0, stream>>>(
        part2, Z2, (const _Float16*)(WhT + (size_t)8 * NH * N), b_down, zbuf, zb, N);
    // 7. outputs
    c1fin_k<<<N / 256, 256, 0, stream>>>(part1, Z1, zbuf, w_deg, b_deg, out, N);
    gemmb_k<64, 64, 0><<<dim3(N / 64, DM / 64, 1), 256, 0, stream>>>(
        (const __hip_bfloat16*)zb, (const __hip_bfloat16*)Wd3T, b_deg3,
        out + (size_t)N * NC + N, N, DM, NH);
}